// Round 6
// baseline (72.001 us; speedup 1.0000x reference)
//
#include <hip/hip_runtime.h>

// ===========================================================================
// Exact algebraic reduction (verified rounds 2-5, absmax <= 1 bf16 ulp):
//   ev_q(b) = e0_q + (e1_q - e0_q) * Podd(b)
//   Podd(b) = 0.5*(1 - cos(t0+W00)cos(t1+W01)cos(t2+W02))
//   e0/e1 from two 512-dim sims (psi0 = V|chi>, psi1 = V X^x9 |chi>).
// Sims live in one wave's registers: 8 complex amps/lane; amp bits 0..2 =
// register (qubits 9,10,11), bits 3..8 = lane (qubits 3..8).
//
// Round-6: sim waves are self-contained — private csn slice per wave (no
// cross-wave barrier before the sim), init products and fused-SU(2) coeffs
// computed per-lane in registers (broadcast LDS reads, all independent).
// Single __syncthreads (eS handoff). One merged measurement butterfly.
// ===========================================================================

typedef float2 cplx;
__device__ inline cplx cmul(cplx a, cplx b) {
  return make_float2(a.x * b.x - a.y * b.y, a.x * b.y + a.y * b.x);
}
__device__ inline cplx cshfl_xor(cplx v, int m) {
  return make_float2(__shfl_xor(v.x, m, 64), __shfl_xor(v.y, m, 64));
}

// --- RY(thy) then RZ(thz) on bit-position BP (0..8) ------------------------
template <int BP>
__device__ inline void rot_gate(cplx (&a)[8], float c, float s, float cz,
                                float sz) {
  if constexpr (BP < 3) {  // register qubit
    constexpr int m = 1 << BP;
#pragma unroll
    for (int r = 0; r < 8; r++)
      if (!(r & m)) {
        const int r1 = r | m;
        const cplx a0 = a[r], a1 = a[r1];
        const float n0x = c * a0.x - s * a1.x, n0y = c * a0.y - s * a1.y;
        const float n1x = s * a0.x + c * a1.x, n1y = s * a0.y + c * a1.y;
        a[r] = make_float2(cz * n0x + sz * n0y, cz * n0y - sz * n0x);
        a[r1] = make_float2(cz * n1x - sz * n1y, cz * n1y + sz * n1x);
      }
  } else {  // lane qubit
    constexpr int lm = 1 << (BP - 3);
    const int bit = (threadIdx.x >> (BP - 3)) & 1;
    const float sy = bit ? s : -s;
    const float so = bit ? -sz : sz;
#pragma unroll
    for (int r = 0; r < 8; r++) {
      const cplx p = cshfl_xor(a[r], lm);
      const float nx = c * a[r].x + sy * p.x, ny = c * a[r].y + sy * p.y;
      a[r] = make_float2(cz * nx + so * ny, cz * ny - so * nx);
    }
  }
}

// --- general SU(2) gate (fused RY*RZ*RY layer) -----------------------------
template <int BP>
__device__ inline void su2_gate(cplx (&a)[8], cplx u00, cplx u01, cplx u10,
                                cplx u11) {
  if constexpr (BP < 3) {
    constexpr int m = 1 << BP;
#pragma unroll
    for (int r = 0; r < 8; r++)
      if (!(r & m)) {
        const int r1 = r | m;
        const cplx a0 = a[r], a1 = a[r1];
        const cplx t0 = cmul(u00, a0), t1 = cmul(u01, a1);
        const cplx t2 = cmul(u10, a0), t3 = cmul(u11, a1);
        a[r] = make_float2(t0.x + t1.x, t0.y + t1.y);
        a[r1] = make_float2(t2.x + t3.x, t2.y + t3.y);
      }
  } else {
    constexpr int lm = 1 << (BP - 3);
    const int bit = (threadIdx.x >> (BP - 3)) & 1;
    const cplx uA = bit ? u11 : u00;
    const cplx uB = bit ? u10 : u01;
#pragma unroll
    for (int r = 0; r < 8; r++) {
      const cplx p = cshfl_xor(a[r], lm);
      const cplx t0 = cmul(uA, a[r]), t1 = cmul(uB, p);
      a[r] = make_float2(t0.x + t1.x, t0.y + t1.y);
    }
  }
}

// --- CNOTs by operand location ---------------------------------------------
template <int CB, int TB>
__device__ inline void cnot_rr(cplx (&a)[8]) {
#pragma unroll
  for (int r = 0; r < 8; r++)
    if ((r & (1 << CB)) && !(r & (1 << TB))) {
      const int r1 = r | (1 << TB);
      const cplx t = a[r];
      a[r] = a[r1];
      a[r1] = t;
    }
}
template <int CB, int TL>
__device__ inline void cnot_rl(cplx (&a)[8]) {
#pragma unroll
  for (int r = 0; r < 8; r++)
    if (r & (1 << CB)) a[r] = cshfl_xor(a[r], 1 << TL);
}
template <int CL, int TB>
__device__ inline void cnot_lr(cplx (&a)[8]) {
  const bool c = (threadIdx.x >> CL) & 1;
#pragma unroll
  for (int r = 0; r < 8; r++)
    if (!(r & (1 << TB))) {
      const int r1 = r | (1 << TB);
      const cplx t0 = a[r];
      a[r] = c ? a[r1] : a[r];
      a[r1] = c ? t0 : a[r1];
    }
}
template <int CL, int TL>
__device__ inline void cnot_ll(cplx (&a)[8]) {
  const bool c = (threadIdx.x >> CL) & 1;
#pragma unroll
  for (int r = 0; r < 8; r++) {
    const cplx p = cshfl_xor(a[r], 1 << TL);
    a[r] = c ? p : a[r];
  }
}

// ===========================================================================
__global__ __launch_bounds__(256) void qnpe_fused(
    const float* __restrict__ cov, const float* __restrict__ dose,
    const float* __restrict__ w, const float* __restrict__ pkb,
    const float* __restrict__ pdb, float* __restrict__ out, int B) {
  __shared__ float csw[2][2][108];  // per-sim-wave private cos/sin tables
  __shared__ float eS[2][9];

  const int tid = threadIdx.x;
  const int b = blockIdx.x * 256 + tid;

  // hoist batch loads above the sim chain (latency overlap)
  float x0 = 0.f, x1 = 0.f, x2 = 0.f;
  if (b < B) {
    x0 = cov[2 * b];
    x1 = cov[2 * b + 1];
    x2 = dose[b];
  }
  const float w0 = w[0], w1 = w[1], w2 = w[2];

  const int wave = tid >> 6;
  const int lane = tid & 63;

  if (wave < 2) {  // wave s simulates psi_s, fully self-contained
    const int s = wave;
    // --- private trig table: lane i fills entries i and 64+i ---------------
    {
      float sn, cs;
      __sincosf(0.5f * w[lane], &sn, &cs);
      csw[s][0][lane] = cs;
      csw[s][1][lane] = sn;
      if (lane < 44) {
        __sincosf(0.5f * w[64 + lane], &sn, &cs);
        csw[s][0][64 + lane] = cs;
        csw[s][1][64 + lane] = sn;
      }
    }
    const float(*csn)[108] = csw[s];  // in-wave visibility: lgkmcnt only

    // --- init: |chi> (layers 0/1 on |0>) with optional X^9 flip ------------
    // factor for qubit 3+j, bit v: v==0 -> (c0*cz, -c0*sz); v==1 -> (s0*cz, s0*sz)
    auto factor = [&](int j, int v) -> cplx {
      const float c0 = csn[0][3 + j], s0 = csn[1][3 + j];
      const float cz = csn[0][15 + j], sz = csn[1][15 + j];
      return v ? make_float2(s0 * cz, s0 * sz) : make_float2(c0 * cz, -c0 * sz);
    };
    cplx P = factor(0, ((lane >> 5) & 1) ^ s);
    P = cmul(P, factor(1, ((lane >> 4) & 1) ^ s));
    P = cmul(P, factor(2, ((lane >> 3) & 1) ^ s));
    P = cmul(P, factor(3, ((lane >> 2) & 1) ^ s));
    P = cmul(P, factor(4, ((lane >> 1) & 1) ^ s));
    P = cmul(P, factor(5, (lane & 1) ^ s));
    const cplx f6[2] = {factor(6, s), factor(6, 1 ^ s)};
    const cplx f7[2] = {factor(7, s), factor(7, 1 ^ s)};
    const cplx f8[2] = {factor(8, s), factor(8, 1 ^ s)};
    cplx a[8];
#pragma unroll
    for (int r = 0; r < 8; r++)
      a[r] = cmul(P, cmul(cmul(f6[(r >> 2) & 1], f7[(r >> 1) & 1]), f8[r & 1]));

#define ROTQ(Q, BP, LY, LZ)                                            \
  rot_gate<BP>(a, csn[0][(LY)*12 + (Q)], csn[1][(LY)*12 + (Q)],        \
               csn[0][(LZ)*12 + (Q)], csn[1][(LZ)*12 + (Q)]);
    // rot layer W2/W3
    ROTQ(3, 8, 2, 3) ROTQ(4, 7, 2, 3) ROTQ(5, 6, 2, 3)
    ROTQ(6, 5, 2, 3) ROTQ(7, 4, 2, 3) ROTQ(8, 3, 2, 3)
    ROTQ(9, 2, 2, 3) ROTQ(10, 1, 2, 3) ROTQ(11, 0, 2, 3)
    // pk ring (3,4)(4,5)(5,6)(6,7)(7,3)
    cnot_ll<5, 4>(a);
    cnot_ll<4, 3>(a);
    cnot_ll<3, 2>(a);
    cnot_ll<2, 1>(a);
    cnot_ll<1, 5>(a);
    // pd ring (8,9)(9,10)(10,11)(11,8)
    cnot_lr<0, 2>(a);
    cnot_rr<2, 1>(a);
    cnot_rr<1, 0>(a);
    cnot_rl<0, 0>(a);
    // rot layer W4/W5
    ROTQ(3, 8, 4, 5) ROTQ(4, 7, 4, 5) ROTQ(5, 6, 4, 5)
    ROTQ(6, 5, 4, 5) ROTQ(7, 4, 4, 5) ROTQ(8, 3, 4, 5)
    ROTQ(9, 2, 4, 5) ROTQ(10, 1, 4, 5) ROTQ(11, 0, 4, 5)
#undef ROTQ

    // fused U = RY(w8)*RZ(w7)*RY(w6) per qubit, computed per-lane in regs.
    // (independent broadcast LDS reads — scheduler can overlap with CNOTs)
    cplx Ug[9][4];
#pragma unroll
    for (int q = 0; q < 9; q++) {
      const float c6 = csn[0][6 * 12 + 3 + q], s6 = csn[1][6 * 12 + 3 + q];
      const float c7 = csn[0][7 * 12 + 3 + q], s7 = csn[1][7 * 12 + 3 + q];
      const float c8 = csn[0][8 * 12 + 3 + q], s8 = csn[1][8 * 12 + 3 + q];
      const cplx M00 = make_float2(c6 * c7, -c6 * s7);
      const cplx M01 = make_float2(-s6 * c7, s6 * s7);
      const cplx M10 = make_float2(s6 * c7, s6 * s7);
      const cplx M11 = make_float2(c6 * c7, c6 * s7);
      Ug[q][0] = make_float2(c8 * M00.x - s8 * M10.x, c8 * M00.y - s8 * M10.y);
      Ug[q][1] = make_float2(c8 * M01.x - s8 * M11.x, c8 * M01.y - s8 * M11.y);
      Ug[q][2] = make_float2(s8 * M00.x + c8 * M10.x, s8 * M00.y + c8 * M10.y);
      Ug[q][3] = make_float2(s8 * M01.x + c8 * M11.x, s8 * M01.y + c8 * M11.y);
    }

    // cross (3,8)(4,9)(5,10)(6,11)(7,8)
    cnot_ll<5, 0>(a);
    cnot_lr<4, 2>(a);
    cnot_lr<3, 1>(a);
    cnot_lr<2, 0>(a);
    cnot_ll<1, 0>(a);
    // fused layer W6/W7/W8
    su2_gate<8>(a, Ug[0][0], Ug[0][1], Ug[0][2], Ug[0][3]);
    su2_gate<7>(a, Ug[1][0], Ug[1][1], Ug[1][2], Ug[1][3]);
    su2_gate<6>(a, Ug[2][0], Ug[2][1], Ug[2][2], Ug[2][3]);
    su2_gate<5>(a, Ug[3][0], Ug[3][1], Ug[3][2], Ug[3][3]);
    su2_gate<4>(a, Ug[4][0], Ug[4][1], Ug[4][2], Ug[4][3]);
    su2_gate<3>(a, Ug[5][0], Ug[5][1], Ug[5][2], Ug[5][3]);
    su2_gate<2>(a, Ug[6][0], Ug[6][1], Ug[6][2], Ug[6][3]);
    su2_gate<1>(a, Ug[7][0], Ug[7][1], Ug[7][2], Ug[7][3]);
    su2_gate<0>(a, Ug[8][0], Ug[8][1], Ug[8][2], Ug[8][3]);

    // --- measurement: one 6-step butterfly for {tot(WHT), v6, v7, v8} ------
    float p[8], tot = 0.f, v6 = 0.f, v7 = 0.f, v8 = 0.f;
#pragma unroll
    for (int r = 0; r < 8; r++) {
      p[r] = a[r].x * a[r].x + a[r].y * a[r].y;
      tot += p[r];
      v6 += ((r >> 2) & 1) ? -p[r] : p[r];
      v7 += ((r >> 1) & 1) ? -p[r] : p[r];
      v8 += (r & 1) ? -p[r] : p[r];
    }
    float v = tot;
#pragma unroll
    for (int k = 0; k < 6; k++) {
      const int m = 1 << k;
      const float pv = __shfl_xor(v, m, 64);
      v = ((lane >> k) & 1) ? (pv - v) : (v + pv);
      v6 += __shfl_xor(v6, m, 64);
      v7 += __shfl_xor(v7, m, 64);
      v8 += __shfl_xor(v8, m, 64);
    }
    // obs ob (0..5) measures lane bit 5-ob -> WHT index 32>>ob
    if (lane == 32) eS[s][0] = v;
    if (lane == 16) eS[s][1] = v;
    if (lane == 8) eS[s][2] = v;
    if (lane == 4) eS[s][3] = v;
    if (lane == 2) eS[s][4] = v;
    if (lane == 1) eS[s][5] = v;
    if (lane == 0) {
      eS[s][6] = v6;
      eS[s][7] = v7;
      eS[s][8] = v8;
    }
  }
  __syncthreads();

  if (b >= B) return;
  const float g = __cosf(x0 + w0) * __cosf(x1 + w1) * __cosf(x2 + w2);
  const float podd = 0.5f * (1.f - g);

#pragma unroll
  for (int q = 0; q < 9; q++) {
    const float e = eS[0][q] + (eS[1][q] - eS[0][q]) * podd;
    const float norm = 0.5f * (e + 1.f);
    if (q < 5) {
      out[b * 5 + q] = pkb[2 * q] + norm * (pkb[2 * q + 1] - pkb[2 * q]);
    } else {
      const int j = q - 5;
      out[B * 5 + b * 4 + j] =
          pdb[2 * j] + norm * (pdb[2 * j + 1] - pdb[2 * j]);
    }
  }
}

// ===========================================================================
extern "C" void kernel_launch(void* const* d_in, const int* in_sizes, int n_in,
                              void* d_out, int out_size, void* d_ws,
                              size_t ws_size, hipStream_t stream) {
  // inputs: 0 subject_ids (unused), 1 covariates (B,2) f32, 2 dose (B,) f32,
  //         3 weights (108,) f32, 4 pk_bounds (5,2) f32, 5 pd_bounds (4,2) f32
  const float* cov = (const float*)d_in[1];
  const float* dose = (const float*)d_in[2];
  const float* wts = (const float*)d_in[3];
  const float* pkb = (const float*)d_in[4];
  const float* pdb = (const float*)d_in[5];
  float* out = (float*)d_out;
  const int B = in_sizes[2];

  hipLaunchKernelGGL(qnpe_fused, dim3((B + 255) / 256), dim3(256), 0, stream,
                     cov, dose, wts, pkb, pdb, out, B);
}